// Round 6
// baseline (59.766 us; speedup 1.0000x reference)
//
#include <hip/hip_runtime.h>

// SNN forward: 2-layer Leaky (subtract reset), BETA=0.95, THRESHOLD=1.0.
// x: [10, B, 4] f32, w1: [5,4] f32, w2: [3,5] f32.
// out: spk2_rec [10,B,3] f32 ++ mem2_rec [10,B,3] f32.
//
// Numerics: bit-identical op sequence to the round-2 passing kernel
// (sequential fmaf dot, unfused mul/add/sub leaky update, mem > 1.0f spike).
//
// Perf structure (round 6):
//  - 1 elem/thread compute; LDS transpose of the block's 256x3 outputs so
//    stores are fully-contiguous f32x4 per lane (full 64B lines per wave,
//    safe for nontemporal streaming stores; round-4 lesson: sub-line nt
//    stores => ~2x HBM write amplification).
//  - DOUBLE-BUFFERED tile => ONE barrier per timestep (was two). WAR hazard
//    two iterations out is fenced by the intervening barrier.
//  - Store phase uses all 4 waves: spk vecs 0..191 by tid<192; mem vecs
//    0..63 by tid>=192, mem vecs 64..191 by tid<128.

#define NUM_STEPS  10
#define NUM_INPUT  4
#define NUM_HIDDEN 5
#define NUM_OUTPUT 3
#define BLOCK      256
#define LSTR       257   // padded LDS row stride -> gather reads <=2-way conflict

typedef float f32x4 __attribute__((ext_vector_type(4)));

__global__ __launch_bounds__(BLOCK) void snn_fwd_kernel(
    const float* __restrict__ x,   // [10, B, 4]
    const float* __restrict__ w1,  // [5, 4]
    const float* __restrict__ w2,  // [3, 5]
    float* __restrict__ out,       // spk2 [10,B,3] ++ mem2 [10,B,3]
    int batch)
{
#pragma clang fp contract(off)
    const int tid        = threadIdx.x;
    const int block_base = blockIdx.x * BLOCK;
    const int b          = block_base + tid;
    const long long B    = (long long)batch;
    const bool full_block = (block_base + BLOCK) <= batch;

    // Threads past the end only exist in partial blocks, whose path has no
    // barriers -> safe early exit.
    if (b >= batch) return;

    // Weights: wave-uniform addresses -> scalar loads, broadcast to lanes.
    float W1[NUM_HIDDEN][NUM_INPUT];
#pragma unroll
    for (int h = 0; h < NUM_HIDDEN; ++h)
#pragma unroll
        for (int i = 0; i < NUM_INPUT; ++i)
            W1[h][i] = w1[h * NUM_INPUT + i];

    float W2[NUM_OUTPUT][NUM_HIDDEN];
#pragma unroll
    for (int o = 0; o < NUM_OUTPUT; ++o)
#pragma unroll
        for (int i = 0; i < NUM_HIDDEN; ++i)
            W2[o][i] = w2[o * NUM_HIDDEN + i];

    float mem1[NUM_HIDDEN] = {0.f, 0.f, 0.f, 0.f, 0.f};
    float mem2[NUM_OUTPUT] = {0.f, 0.f, 0.f};

    float* __restrict__ spk_out = out;                                    // [10,B,3]
    float* __restrict__ mem_out = out + (long long)NUM_STEPS * B * NUM_OUTPUT;

    // Double-buffered [stream(2)][o(3)][tid] tile, padded row stride.
    __shared__ float tile[2][6 * LSTR];

    if (full_block) {
#pragma unroll
        for (int t = 0; t < NUM_STEPS; ++t) {
            float* __restrict__ tl = tile[t & 1];

            // Coalesced 16B/lane load of this timestep's input row.
            const f32x4 xv = reinterpret_cast<const f32x4*>(
                x + ((long long)t * B + block_base) * NUM_INPUT)[tid];
            const float xd[NUM_INPUT] = {xv.x, xv.y, xv.z, xv.w};

            // Layer 1: sequential fma from 0, then unfused leaky update.
            float spk1[NUM_HIDDEN];
#pragma unroll
            for (int h = 0; h < NUM_HIDDEN; ++h) {
                float acc = 0.0f;
#pragma unroll
                for (int i = 0; i < NUM_INPUT; ++i)
                    acc = fmaf(xd[i], W1[h][i], acc);
                const float reset = (mem1[h] > 1.0f) ? 1.0f : 0.0f;  // prev mem
                const float t1 = __fmul_rn(0.95f, mem1[h]);
                const float t2 = __fadd_rn(t1, acc);
                mem1[h] = __fsub_rn(t2, reset);
                spk1[h] = (mem1[h] > 1.0f) ? 1.0f : 0.0f;
            }

            // Layer 2 -> stage outputs in LDS (stride-1 writes, no conflicts).
#pragma unroll
            for (int o = 0; o < NUM_OUTPUT; ++o) {
                float acc = 0.0f;
#pragma unroll
                for (int i = 0; i < NUM_HIDDEN; ++i)
                    acc = fmaf(spk1[i], W2[o][i], acc);
                const float reset = (mem2[o] > 1.0f) ? 1.0f : 0.0f;
                const float t1 = __fmul_rn(0.95f, mem2[o]);
                const float t2 = __fadd_rn(t1, acc);
                mem2[o] = __fsub_rn(t2, reset);
                tl[o * LSTR + tid]       = (mem2[o] > 1.0f) ? 1.0f : 0.0f;
                tl[(o + 3) * LSTR + tid] = mem2[o];
            }

            __syncthreads();   // single barrier per timestep (double buffer)

            // Cooperative transposed stores: 192 f32x4 per stream, balanced
            // across all 4 waves, fully contiguous -> nt streaming stores.
            const long long base = ((long long)t * B + block_base) * NUM_OUTPUT;
            if (tid < 192) {           // spk vecs 0..191 (waves 0..2)
                f32x4 sv;
#pragma unroll
                for (int c = 0; c < 4; ++c) {
                    const int f = tid * 4 + c;
                    sv[c] = tl[(f % 3) * LSTR + (f / 3)];
                }
                __builtin_nontemporal_store(
                    sv, reinterpret_cast<f32x4*>(spk_out + base) + tid);
            } else {                   // mem vecs 0..63 (wave 3)
                const int v = tid - 192;
                f32x4 mv;
#pragma unroll
                for (int c = 0; c < 4; ++c) {
                    const int f = v * 4 + c;
                    mv[c] = tl[(f % 3 + 3) * LSTR + (f / 3)];
                }
                __builtin_nontemporal_store(
                    mv, reinterpret_cast<f32x4*>(mem_out + base) + v);
            }
            if (tid < 128) {           // mem vecs 64..191 (waves 0..1)
                const int v = 64 + tid;
                f32x4 mv;
#pragma unroll
                for (int c = 0; c < 4; ++c) {
                    const int f = v * 4 + c;
                    mv[c] = tl[(f % 3 + 3) * LSTR + (f / 3)];
                }
                __builtin_nontemporal_store(
                    mv, reinterpret_cast<f32x4*>(mem_out + base) + v);
            }
            // no second barrier: next timestep writes the other tile buffer;
            // reuse of THIS buffer (t+2) is fenced by the t+1 barrier.
        }
    } else {
        // Partial tail block: scalar path (no barriers).
#pragma unroll
        for (int t = 0; t < NUM_STEPS; ++t) {
            const f32x4 xv = *reinterpret_cast<const f32x4*>(
                x + ((long long)t * B + b) * NUM_INPUT);
            const float xd[NUM_INPUT] = {xv.x, xv.y, xv.z, xv.w};

            float spk1[NUM_HIDDEN];
#pragma unroll
            for (int h = 0; h < NUM_HIDDEN; ++h) {
                float acc = 0.0f;
#pragma unroll
                for (int i = 0; i < NUM_INPUT; ++i)
                    acc = fmaf(xd[i], W1[h][i], acc);
                const float reset = (mem1[h] > 1.0f) ? 1.0f : 0.0f;
                const float t1 = __fmul_rn(0.95f, mem1[h]);
                const float t2 = __fadd_rn(t1, acc);
                mem1[h] = __fsub_rn(t2, reset);
                spk1[h] = (mem1[h] > 1.0f) ? 1.0f : 0.0f;
            }

            const long long base = ((long long)t * B + b) * NUM_OUTPUT;
#pragma unroll
            for (int o = 0; o < NUM_OUTPUT; ++o) {
                float acc = 0.0f;
#pragma unroll
                for (int i = 0; i < NUM_HIDDEN; ++i)
                    acc = fmaf(spk1[i], W2[o][i], acc);
                const float reset = (mem2[o] > 1.0f) ? 1.0f : 0.0f;
                const float t1 = __fmul_rn(0.95f, mem2[o]);
                const float t2 = __fadd_rn(t1, acc);
                mem2[o] = __fsub_rn(t2, reset);
                spk_out[base + o] = (mem2[o] > 1.0f) ? 1.0f : 0.0f;
                mem_out[base + o] = mem2[o];
            }
        }
    }
}

extern "C" void kernel_launch(void* const* d_in, const int* in_sizes, int n_in,
                              void* d_out, int out_size, void* d_ws, size_t ws_size,
                              hipStream_t stream)
{
    const float* x  = (const float*)d_in[0];
    const float* w1 = (const float*)d_in[1];
    const float* w2 = (const float*)d_in[2];
    float* out = (float*)d_out;

    const int batch = in_sizes[0] / (NUM_STEPS * NUM_INPUT);

    const int grid = (batch + BLOCK - 1) / BLOCK;
    snn_fwd_kernel<<<grid, BLOCK, 0, stream>>>(x, w1, w2, out, batch);
}